// Round 6
// baseline (3043.442 us; speedup 1.0000x reference)
//
#include <hip/hip_runtime.h>
#include <hip/hip_bf16.h>
#include <cmath>

#define N_NODES 50000
#define N_EDGES 800000
#define NODE_DIM 128
#define EDGE_DIM 100
#define EMB_DIM 92
#define N_GRAPHS 256

__device__ __forceinline__ float softplus_f(float v) {
    return v > 20.0f ? v : __logf(1.0f + __expf(v));
}
__device__ __forceinline__ float sigmoid_f(float v) {
    return 1.0f / (1.0f + __expf(-v));
}

// ---------------------------------------------------------------- CSR build
__global__ void deg_kernel(const int* __restrict__ ei, int* __restrict__ deg) {
    int e = blockIdx.x * blockDim.x + threadIdx.x;
    if (e >= N_EDGES) return;
    atomicAdd(&deg[ei[N_EDGES + e]], 1);
}

#define SB 1024
__global__ void scan1_kernel(const int* __restrict__ deg, int* __restrict__ rp,
                             int* __restrict__ bsum) {
    __shared__ int buf[SB];
    int b = blockIdx.x, t = threadIdx.x, i = b * SB + t;
    int v = (i < N_NODES) ? deg[i] : 0;
    buf[t] = v;
    __syncthreads();
    for (int off = 1; off < SB; off <<= 1) {
        int a = (t >= off) ? buf[t - off] : 0;
        __syncthreads();
        buf[t] += a;
        __syncthreads();
    }
    if (i < N_NODES) rp[i] = buf[t] - v;
    if (t == SB - 1) bsum[b] = buf[t];
}
__global__ void scan2_kernel(int* __restrict__ bsum, int n) {
    if (threadIdx.x == 0) {
        int s = 0;
        for (int i = 0; i < n; i++) { int v = bsum[i]; bsum[i] = s; s += v; }
    }
}
__global__ void scan3_kernel(int* __restrict__ rp, const int* __restrict__ bsum) {
    int i = blockIdx.x * SB + threadIdx.x;
    if (i < N_NODES) rp[i] += bsum[blockIdx.x];
    if (i == 0) rp[N_NODES] = N_EDGES;
}

// fill CSR slots; distance computed inline
__global__ void fill_kernel(const int* __restrict__ ei, const float* __restrict__ R,
                            const int* __restrict__ row_ptr, int* __restrict__ cnt2,
                            int* __restrict__ s_src, int* __restrict__ s_dst,
                            float* __restrict__ s_d) {
    int e = blockIdx.x * blockDim.x + threadIdx.x;
    if (e >= N_EDGES) return;
    int s = ei[e];
    int dst = ei[N_EDGES + e];
    float dx = R[3 * s + 0] - R[3 * dst + 0];
    float dy = R[3 * s + 1] - R[3 * dst + 1];
    float dz = R[3 * s + 2] - R[3 * dst + 2];
    float d = sqrtf(dx * dx + dy * dy + dz * dz);
    int pos = row_ptr[dst] + atomicAdd(&cnt2[dst], 1);
    s_src[pos] = s;
    s_dst[pos] = dst;
    s_d[pos] = d;
}

// ---------------------------------------------------------------- graph boundaries
__global__ void gb_kernel(const int* __restrict__ batch, int* __restrict__ gs) {
    int i = blockIdx.x * 256 + threadIdx.x;
    if (i > N_NODES) return;
    int b = (i < N_NODES) ? batch[i] : N_GRAPHS;
    int pb = (i == 0) ? -1 : batch[i - 1];
    for (int g = pb + 1; g <= b; g++) gs[g] = i;
}

// ---------------------------------------------------------------- We -> bf16
__global__ void wcvt_kernel(const float* __restrict__ conv_w, __hip_bfloat16* __restrict__ Webf) {
    int i = blockIdx.x * 256 + threadIdx.x;
    if (i >= 3 * EDGE_DIM * 256) return;
    int l = i / (EDGE_DIM * 256), r = i - l * (EDGE_DIM * 256);
    Webf[i] = (__hip_bfloat16)conv_w[(size_t)l * 356 * 256 + 256 * 256 + r];
}

// ---------------------------------------------------------------- embedding
__global__ void embed_kernel(const int* __restrict__ z, const float* __restrict__ emb,
                             const float* __restrict__ emb_w, const float* __restrict__ emb_b,
                             float* __restrict__ x) {
    __shared__ float er[EMB_DIM * 8];
    __shared__ int zi[8];
    int base = blockIdx.x * 8;
    int t = threadIdx.x;  // 0..127
    if (t < 8) zi[t] = z[base + t];
    __syncthreads();
    for (int idx = t; idx < EMB_DIM * 8; idx += 128) {
        int k = idx >> 3, j = idx & 7;
        er[idx] = emb[zi[j] * EMB_DIM + k];
    }
    __syncthreads();
    float acc[8];
    float bb = emb_b[t];
#pragma unroll
    for (int j = 0; j < 8; j++) acc[j] = bb;
    for (int k = 0; k < EMB_DIM; k++) {
        float w = emb_w[k * NODE_DIM + t];
        float4 ja = *(const float4*)&er[k * 8];
        float4 jb = *(const float4*)&er[k * 8 + 4];
        acc[0] = fmaf(w, ja.x, acc[0]); acc[1] = fmaf(w, ja.y, acc[1]);
        acc[2] = fmaf(w, ja.z, acc[2]); acc[3] = fmaf(w, ja.w, acc[3]);
        acc[4] = fmaf(w, jb.x, acc[4]); acc[5] = fmaf(w, jb.y, acc[5]);
        acc[6] = fmaf(w, jb.z, acc[6]); acc[7] = fmaf(w, jb.w, acc[7]);
    }
#pragma unroll
    for (int j = 0; j < 8; j++) x[(base + j) * NODE_DIM + t] = acc[j];
}

// ---------------------------------------------------------------- node pre-GEMM (16 nodes/block)
#define NPB2 16
__global__ __launch_bounds__(256) void node_pre_kernel(
    const float* __restrict__ x, const float* __restrict__ Wl,
    const float* __restrict__ bl, float* __restrict__ P1, float* __restrict__ P2) {
    __shared__ float xs[NODE_DIM * NPB2];
    int base = blockIdx.x * NPB2;
    int t = threadIdx.x;  // 0..255 output channel
    for (int idx = t; idx < NODE_DIM * NPB2; idx += 256) {
        int j = idx >> 7, k = idx & 127;
        xs[k * NPB2 + j] = x[(base + j) * NODE_DIM + k];
    }
    __syncthreads();
    float a1[NPB2], a2[NPB2];
#pragma unroll
    for (int j = 0; j < NPB2; j++) { a1[j] = 0.f; a2[j] = 0.f; }
    const float* W1 = Wl;
    const float* W2 = Wl + NODE_DIM * 256;
    for (int k = 0; k < NODE_DIM; k++) {
        float w1 = W1[k * 256 + t];
        float w2 = W2[k * 256 + t];
#pragma unroll
        for (int jj = 0; jj < NPB2; jj += 4) {
            float4 xj = *(const float4*)&xs[k * NPB2 + jj];
            a1[jj + 0] = fmaf(w1, xj.x, a1[jj + 0]);
            a1[jj + 1] = fmaf(w1, xj.y, a1[jj + 1]);
            a1[jj + 2] = fmaf(w1, xj.z, a1[jj + 2]);
            a1[jj + 3] = fmaf(w1, xj.w, a1[jj + 3]);
            a2[jj + 0] = fmaf(w2, xj.x, a2[jj + 0]);
            a2[jj + 1] = fmaf(w2, xj.y, a2[jj + 1]);
            a2[jj + 2] = fmaf(w2, xj.z, a2[jj + 2]);
            a2[jj + 3] = fmaf(w2, xj.w, a2[jj + 3]);
        }
    }
    float bb = bl[t];
#pragma unroll
    for (int j = 0; j < NPB2; j++) {
        P1[(base + j) * 256 + t] = a1[j] + bb;
        P2[(base + j) * 256 + t] = a2[j];
    }
}

// ---------------------------------------------------------------- edge msg v6
// Half-wave (32 lanes) owns 80 CONTIGUOUS dst-sorted edges. We read from global
// (L2-resident, no LDS staging, no barriers). In-register run merge; flush via
// 512B LDS bounce -> channel-contiguous dword atomics (dense 128B EA sectors).
// Only LDS = 4KB scratch -> occupancy VGPR-limited (~6 waves/SIMD).
#define NT 10
#define EHW 80   // edges per half-wave
#define EPB3 (EHW * 8)  // 640 edges/block; 1250 blocks
__global__ __launch_bounds__(256, 6) void edge_fused5(
    const int* __restrict__ s_src, const int* __restrict__ s_dst,
    const float* __restrict__ s_d,
    const float* __restrict__ P1, const float* __restrict__ P2,
    const __hip_bfloat16* __restrict__ Webf, float* __restrict__ agg) {
    __shared__ float sc[8 * 128];  // 4096 B flush-bounce, 512B per half-wave
    const float sp_ = 6.0f / 99.0f;
    const float inv_s = 99.0f / 6.0f;
    const float coeff = -0.5f * inv_s * inv_s;
    int t = threadIdx.x;
    int q = t & 31;    // channel quad: compute layout ch 4q..4q+3 (z1), 128+4q.. (z2)
    int hw = t >> 5;   // half-wave 0..7
    float* myc = &sc[hw * 128];
    int e_base = blockIdx.x * EPB3 + hw * EHW;
    float4 run = make_float4(0.f, 0.f, 0.f, 0.f);
    int cur = -1;
    for (int i0 = 0; i0 < EHW; i0 += 4) {
        int eh = e_base + i0;
        int4 sc4 = *(const int4*)&s_src[eh];
        int4 dd4 = *(const int4*)&s_dst[eh];
        float4 dv4 = *(const float4*)&s_d[eh];
        int scs[4] = {sc4.x, sc4.y, sc4.z, sc4.w};
        int dds[4] = {dd4.x, dd4.y, dd4.z, dd4.w};
        float dvs[4] = {dv4.x, dv4.y, dv4.z, dv4.w};
        float4 a1[4], a2[4];
#pragma unroll
        for (int m = 0; m < 4; m++) {
            const float4* p1 = (const float4*)&P1[(size_t)dds[m] * 256];
            const float4* p2 = (const float4*)&P2[(size_t)scs[m] * 256];
            float4 p1a = p1[q], p2a = p2[q];
            float4 p1b = p1[32 + q], p2b = p2[32 + q];
            a1[m] = make_float4(p1a.x + p2a.x, p1a.y + p2a.y, p1a.z + p2a.z, p1a.w + p2a.w);
            a2[m] = make_float4(p1b.x + p2b.x, p1b.y + p2b.y, p1b.z + p2b.z, p1b.w + p2b.w);
        }
#pragma unroll
        for (int m = 0; m < 4; m++) {
            float dv = dvs[m];
            if (dv <= 6.34f) {  // taps beyond are < 3e-7
                int k0 = max(0, min(EDGE_DIM - NT, (int)ceilf(dv * inv_s - 4.5f)));
#pragma unroll
                for (int i = 0; i < NT; i++) {
                    float df = dv - (float)(k0 + i) * sp_;
                    float e = __expf(coeff * df * df);
                    const uint2* row = (const uint2*)(Webf + (size_t)(k0 + i) * 256);
                    uint2 u1 = row[q];        // z1 ch 4q..4q+3 (bf16x4)
                    uint2 u2 = row[32 + q];   // z2 ch 128+4q..
                    a1[m].x = fmaf(__uint_as_float(u1.x << 16), e, a1[m].x);
                    a1[m].y = fmaf(__uint_as_float(u1.x & 0xffff0000u), e, a1[m].y);
                    a1[m].z = fmaf(__uint_as_float(u1.y << 16), e, a1[m].z);
                    a1[m].w = fmaf(__uint_as_float(u1.y & 0xffff0000u), e, a1[m].w);
                    a2[m].x = fmaf(__uint_as_float(u2.x << 16), e, a2[m].x);
                    a2[m].y = fmaf(__uint_as_float(u2.x & 0xffff0000u), e, a2[m].y);
                    a2[m].z = fmaf(__uint_as_float(u2.y << 16), e, a2[m].z);
                    a2[m].w = fmaf(__uint_as_float(u2.y & 0xffff0000u), e, a2[m].w);
                }
            }
        }
#pragma unroll
        for (int m = 0; m < 4; m++) {
            float4 mg;
            mg.x = sigmoid_f(a1[m].x) * softplus_f(a2[m].x);
            mg.y = sigmoid_f(a1[m].y) * softplus_f(a2[m].y);
            mg.z = sigmoid_f(a1[m].z) * softplus_f(a2[m].z);
            mg.w = sigmoid_f(a1[m].w) * softplus_f(a2[m].w);
            if (dds[m] != cur) {
                if (cur >= 0) {
                    // bounce through LDS: write compute layout, read channel-strided
                    *(float4*)&myc[4 * q] = run;
                    float* ag = &agg[(size_t)cur * NODE_DIM];
#pragma unroll
                    for (int j = 0; j < 4; j++)
                        atomicAdd(ag + q + 32 * j, myc[q + 32 * j]);
                }
                cur = dds[m];
                run = mg;
            } else {
                run.x += mg.x; run.y += mg.y; run.z += mg.z; run.w += mg.w;
            }
        }
    }
    if (cur >= 0) {
        *(float4*)&myc[4 * q] = run;
        float* ag = &agg[(size_t)cur * NODE_DIM];
#pragma unroll
        for (int j = 0; j < 4; j++)
            atomicAdd(ag + q + 32 * j, myc[q + 32 * j]);
    }
}

// ---------------------------------------------------------------- layernorm + residual + softplus
__global__ void ln_kernel(const float* __restrict__ agg, const float* __restrict__ g,
                          const float* __restrict__ b, float* __restrict__ x) {
    __shared__ float sm[4][2];
    int t = threadIdx.x;
    int r = blockIdx.x * 2 + (t >> 7);
    int c = t & 127;
    float a = agg[(size_t)r * 128 + c];
    float s1 = a, s2 = a * a;
#pragma unroll
    for (int off = 32; off > 0; off >>= 1) {
        s1 += __shfl_xor(s1, off);
        s2 += __shfl_xor(s2, off);
    }
    int wv = t >> 6;
    if ((t & 63) == 0) { sm[wv][0] = s1; sm[wv][1] = s2; }
    __syncthreads();
    int w0 = (t >> 7) * 2;
    float S1 = sm[w0][0] + sm[w0 + 1][0];
    float S2 = sm[w0][1] + sm[w0 + 1][1];
    float mu = S1 * (1.0f / 128.0f);
    float var = S2 * (1.0f / 128.0f) - mu * mu;
    float rstd = rsqrtf(fmaxf(var, 0.f) + 1e-5f);
    float xv = x[(size_t)r * 128 + c];
    x[(size_t)r * 128 + c] = softplus_f((a - mu) * rstd * g[c] + b[c] + xv);
}

// ---------------------------------------------------------------- fused mean-pool + MLP head
__global__ void pool_head_kernel(const float* __restrict__ x, const int* __restrict__ gs,
                                 const float* __restrict__ cfc_w, const float* __restrict__ cfc_b,
                                 const float* __restrict__ fc_w, const float* __restrict__ fc_b,
                                 const float* __restrict__ out_w, const float* __restrict__ out_b,
                                 float* __restrict__ out) {
    int g = blockIdx.x, c = threadIdx.x;  // 128 threads
    int n0 = gs[g], n1 = gs[g + 1];
    float s = 0.f;
    for (int n = n0; n < n1; n++) s += x[(size_t)n * 128 + c];
    __shared__ float h[128], h2[128];
    h[c] = s / fmaxf((float)(n1 - n0), 1.0f);
    __syncthreads();
    float acc = cfc_b[c];
    for (int k = 0; k < 128; k++) acc = fmaf(h[k], cfc_w[k * 128 + c], acc);
    h2[c] = softplus_f(acc);
    __syncthreads();
    for (int l = 0; l < 2; l++) {
        const float* W = fc_w + l * 128 * 128;
        acc = fc_b[l * 128 + c];
        for (int k = 0; k < 128; k++) acc = fmaf(h2[k], W[k * 128 + c], acc);
        __syncthreads();
        h2[c] = softplus_f(acc);
        __syncthreads();
    }
    h[c] = h2[c] * out_w[c];
    __syncthreads();
    for (int off = 64; off > 0; off >>= 1) {
        if (c < off) h[c] += h[c + off];
        __syncthreads();
    }
    if (c == 0) out[g] = h[0] + out_b[0];
}

// ---------------------------------------------------------------- launcher
extern "C" void kernel_launch(void* const* d_in, const int* in_sizes, int n_in,
                              void* d_out, int out_size, void* d_ws, size_t ws_size,
                              hipStream_t stream) {
    const int*   z      = (const int*)d_in[0];
    const float* R      = (const float*)d_in[1];
    const int*   ei     = (const int*)d_in[2];
    const int*   batch  = (const int*)d_in[3];
    const float* emb    = (const float*)d_in[4];
    const float* emb_w  = (const float*)d_in[5];
    const float* emb_b  = (const float*)d_in[6];
    const float* conv_w = (const float*)d_in[7];
    const float* conv_b = (const float*)d_in[8];
    const float* ln_g   = (const float*)d_in[9];
    const float* ln_b   = (const float*)d_in[10];
    const float* cfc_w  = (const float*)d_in[11];
    const float* cfc_b  = (const float*)d_in[12];
    const float* fc_w   = (const float*)d_in[13];
    const float* fc_b   = (const float*)d_in[14];
    const float* out_w  = (const float*)d_in[15];
    const float* out_b  = (const float*)d_in[16];
    float* out = (float*)d_out;

    float* ws    = (float*)d_ws;
    float* x     = ws;                     // 6,400,000
    float* agg   = x + 6400000;            // 6,400,000
    float* P1    = agg + 6400000;          // 12,800,000
    float* P2    = P1 + 12800000;          // 12,800,000
    float* s_d   = P2 + 12800000;          // 800,000
    int* s_src   = (int*)(s_d + 800000);   // 800,000
    int* s_dst   = s_src + 800000;         // 800,000
    int* row_ptr = s_dst + 800000;         // 50,004
    int* deg     = row_ptr + 50004;        // 50,000
    int* cnt2    = deg + 50000;            // 50,000
    int* bsum    = cnt2 + 50000;           // 64
    int* gs      = bsum + 64;              // 260
    __hip_bfloat16* Webf = (__hip_bfloat16*)(gs + 260);  // 76,800 bf16

    hipMemsetAsync(deg, 0, (size_t)100000 * 4, stream);
    deg_kernel<<<(N_EDGES + 255) / 256, 256, 0, stream>>>(ei, deg);
    int nsb = (N_NODES + SB - 1) / SB;  // 49
    scan1_kernel<<<nsb, SB, 0, stream>>>(deg, row_ptr, bsum);
    scan2_kernel<<<1, 64, 0, stream>>>(bsum, nsb);
    scan3_kernel<<<nsb, SB, 0, stream>>>(row_ptr, bsum);
    fill_kernel<<<(N_EDGES + 255) / 256, 256, 0, stream>>>(ei, R, row_ptr, cnt2,
                                                           s_src, s_dst, s_d);
    gb_kernel<<<(N_NODES + 256) / 256 + 1, 256, 0, stream>>>(batch, gs);
    wcvt_kernel<<<(3 * EDGE_DIM * 256 + 255) / 256, 256, 0, stream>>>(conv_w, Webf);

    embed_kernel<<<N_NODES / 8, 128, 0, stream>>>(z, emb, emb_w, emb_b, x);
    for (int l = 0; l < 3; l++) {
        const float* Wl = conv_w + (size_t)l * 356 * 256;
        node_pre_kernel<<<N_NODES / NPB2, 256, 0, stream>>>(x, Wl, conv_b + l * 256, P1, P2);
        hipMemsetAsync(agg, 0, (size_t)6400000 * 4, stream);
        edge_fused5<<<N_EDGES / EPB3, 256, 0, stream>>>(s_src, s_dst, s_d, P1, P2,
                                                        Webf + (size_t)l * EDGE_DIM * 256, agg);
        ln_kernel<<<N_NODES / 2, 256, 0, stream>>>(agg, ln_g + l * 128, ln_b + l * 128, x);
    }
    pool_head_kernel<<<N_GRAPHS, 128, 0, stream>>>(x, gs, cfc_w, cfc_b, fc_w, fc_b,
                                                   out_w, out_b, out);
}

// Round 7
// 1412.792 us; speedup vs baseline: 2.1542x; 2.1542x over previous
//
#include <hip/hip_runtime.h>
#include <hip/hip_bf16.h>
#include <cmath>

#define N_NODES 50000
#define N_EDGES 800000
#define NODE_DIM 128
#define EDGE_DIM 100
#define EMB_DIM 92
#define N_GRAPHS 256

__device__ __forceinline__ float softplus_f(float v) {
    return v > 20.0f ? v : __logf(1.0f + __expf(v));
}
__device__ __forceinline__ float sigmoid_f(float v) {
    return 1.0f / (1.0f + __expf(-v));
}

// ---------------------------------------------------------------- CSR build
__global__ void deg_kernel(const int* __restrict__ ei, int* __restrict__ deg) {
    int e = blockIdx.x * blockDim.x + threadIdx.x;
    if (e >= N_EDGES) return;
    atomicAdd(&deg[ei[N_EDGES + e]], 1);
}

#define SB 1024
__global__ void scan1_kernel(const int* __restrict__ deg, int* __restrict__ rp,
                             int* __restrict__ bsum) {
    __shared__ int buf[SB];
    int b = blockIdx.x, t = threadIdx.x, i = b * SB + t;
    int v = (i < N_NODES) ? deg[i] : 0;
    buf[t] = v;
    __syncthreads();
    for (int off = 1; off < SB; off <<= 1) {
        int a = (t >= off) ? buf[t - off] : 0;
        __syncthreads();
        buf[t] += a;
        __syncthreads();
    }
    if (i < N_NODES) rp[i] = buf[t] - v;
    if (t == SB - 1) bsum[b] = buf[t];
}
__global__ void scan2_kernel(int* __restrict__ bsum, int n) {
    if (threadIdx.x == 0) {
        int s = 0;
        for (int i = 0; i < n; i++) { int v = bsum[i]; bsum[i] = s; s += v; }
    }
}
__global__ void scan3_kernel(int* __restrict__ rp, const int* __restrict__ bsum) {
    int i = blockIdx.x * SB + threadIdx.x;
    if (i < N_NODES) rp[i] += bsum[blockIdx.x];
    if (i == 0) rp[N_NODES] = N_EDGES;
}

// fill CSR slots; distance computed inline
__global__ void fill_kernel(const int* __restrict__ ei, const float* __restrict__ R,
                            const int* __restrict__ row_ptr, int* __restrict__ cnt2,
                            int* __restrict__ s_src, int* __restrict__ s_dst,
                            float* __restrict__ s_d) {
    int e = blockIdx.x * blockDim.x + threadIdx.x;
    if (e >= N_EDGES) return;
    int s = ei[e];
    int dst = ei[N_EDGES + e];
    float dx = R[3 * s + 0] - R[3 * dst + 0];
    float dy = R[3 * s + 1] - R[3 * dst + 1];
    float dz = R[3 * s + 2] - R[3 * dst + 2];
    float d = sqrtf(dx * dx + dy * dy + dz * dz);
    int pos = row_ptr[dst] + atomicAdd(&cnt2[dst], 1);
    s_src[pos] = s;
    s_dst[pos] = dst;
    s_d[pos] = d;
}

// ---------------------------------------------------------------- graph boundaries
__global__ void gb_kernel(const int* __restrict__ batch, int* __restrict__ gs) {
    int i = blockIdx.x * 256 + threadIdx.x;
    if (i > N_NODES) return;
    int b = (i < N_NODES) ? batch[i] : N_GRAPHS;
    int pb = (i == 0) ? -1 : batch[i - 1];
    for (int g = pb + 1; g <= b; g++) gs[g] = i;
}

// ---------------------------------------------------------------- We -> bf16
__global__ void wcvt_kernel(const float* __restrict__ conv_w, __hip_bfloat16* __restrict__ Webf) {
    int i = blockIdx.x * 256 + threadIdx.x;
    if (i >= 3 * EDGE_DIM * 256) return;
    int l = i / (EDGE_DIM * 256), r = i - l * (EDGE_DIM * 256);
    Webf[i] = (__hip_bfloat16)conv_w[(size_t)l * 356 * 256 + 256 * 256 + r];
}

// ---------------------------------------------------------------- embedding
__global__ void embed_kernel(const int* __restrict__ z, const float* __restrict__ emb,
                             const float* __restrict__ emb_w, const float* __restrict__ emb_b,
                             float* __restrict__ x) {
    __shared__ float er[EMB_DIM * 8];
    __shared__ int zi[8];
    int base = blockIdx.x * 8;
    int t = threadIdx.x;  // 0..127
    if (t < 8) zi[t] = z[base + t];
    __syncthreads();
    for (int idx = t; idx < EMB_DIM * 8; idx += 128) {
        int k = idx >> 3, j = idx & 7;
        er[idx] = emb[zi[j] * EMB_DIM + k];
    }
    __syncthreads();
    float acc[8];
    float bb = emb_b[t];
#pragma unroll
    for (int j = 0; j < 8; j++) acc[j] = bb;
    for (int k = 0; k < EMB_DIM; k++) {
        float w = emb_w[k * NODE_DIM + t];
        float4 ja = *(const float4*)&er[k * 8];
        float4 jb = *(const float4*)&er[k * 8 + 4];
        acc[0] = fmaf(w, ja.x, acc[0]); acc[1] = fmaf(w, ja.y, acc[1]);
        acc[2] = fmaf(w, ja.z, acc[2]); acc[3] = fmaf(w, ja.w, acc[3]);
        acc[4] = fmaf(w, jb.x, acc[4]); acc[5] = fmaf(w, jb.y, acc[5]);
        acc[6] = fmaf(w, jb.z, acc[6]); acc[7] = fmaf(w, jb.w, acc[7]);
    }
#pragma unroll
    for (int j = 0; j < 8; j++) x[(base + j) * NODE_DIM + t] = acc[j];
}

// ---------------------------------------------------------------- node pre-GEMM (16 nodes/block)
#define NPB2 16
__global__ __launch_bounds__(256) void node_pre_kernel(
    const float* __restrict__ x, const float* __restrict__ Wl,
    const float* __restrict__ bl, float* __restrict__ P1, float* __restrict__ P2) {
    __shared__ float xs[NODE_DIM * NPB2];
    int base = blockIdx.x * NPB2;
    int t = threadIdx.x;  // 0..255 output channel
    for (int idx = t; idx < NODE_DIM * NPB2; idx += 256) {
        int j = idx >> 7, k = idx & 127;
        xs[k * NPB2 + j] = x[(base + j) * NODE_DIM + k];
    }
    __syncthreads();
    float a1[NPB2], a2[NPB2];
#pragma unroll
    for (int j = 0; j < NPB2; j++) { a1[j] = 0.f; a2[j] = 0.f; }
    const float* W1 = Wl;
    const float* W2 = Wl + NODE_DIM * 256;
    for (int k = 0; k < NODE_DIM; k++) {
        float w1 = W1[k * 256 + t];
        float w2 = W2[k * 256 + t];
#pragma unroll
        for (int jj = 0; jj < NPB2; jj += 4) {
            float4 xj = *(const float4*)&xs[k * NPB2 + jj];
            a1[jj + 0] = fmaf(w1, xj.x, a1[jj + 0]);
            a1[jj + 1] = fmaf(w1, xj.y, a1[jj + 1]);
            a1[jj + 2] = fmaf(w1, xj.z, a1[jj + 2]);
            a1[jj + 3] = fmaf(w1, xj.w, a1[jj + 3]);
            a2[jj + 0] = fmaf(w2, xj.x, a2[jj + 0]);
            a2[jj + 1] = fmaf(w2, xj.y, a2[jj + 1]);
            a2[jj + 2] = fmaf(w2, xj.z, a2[jj + 2]);
            a2[jj + 3] = fmaf(w2, xj.w, a2[jj + 3]);
        }
    }
    float bb = bl[t];
#pragma unroll
    for (int j = 0; j < NPB2; j++) {
        P1[(base + j) * 256 + t] = a1[j] + bb;
        P2[(base + j) * 256 + t] = a2[j];
    }
}

// ---------------------------------------------------------------- edge msg (round-4 structure)
// dst-sorted edges, EPB per block in chunks of 32. Sparse 10-tap window, bf16 We
// in LDS, fast softplus epilogue, channel-contiguous segmented-reduce atomics
// (proven dense: WRITE ~48 MB). EPB=800 amortizes the 51.2 KB WeL stage over
// 3.1x more edges than round 4 (We re-read traffic 160 -> 51 MB/layer).
#define NT 10
#define EG2 32
#define EPB 800  // 1000 blocks
__global__ __launch_bounds__(256, 2) void edge_fused3(
    const int* __restrict__ s_src, const int* __restrict__ s_dst,
    const float* __restrict__ s_d,
    const float* __restrict__ P1, const float* __restrict__ P2,
    const __hip_bfloat16* __restrict__ Webf, float* __restrict__ agg) {
    __shared__ __hip_bfloat16 WeL[EDGE_DIM * 256];  // 51200 B
    __shared__ float msgL[EG2 * 128];               // 16384 B
    __shared__ float eaL[EG2 * NT];                 // 1280 B
    __shared__ int dstL[EG2];
    int t = threadIdx.x;
    {  // stage We once: 3200 x 16B
        const float4* s4 = (const float4*)Webf;
        float4* d4 = (float4*)WeL;
        for (int i = t; i < 3200; i += 256) d4[i] = s4[i];
    }
    const float sp_ = 6.0f / 99.0f;
    const float inv_s = 99.0f / 6.0f;
    const float coeff = -0.5f * inv_s * inv_s;
    int w = t >> 6, lane = t & 63, h = lane >> 5, q = lane & 31;
    int base0 = blockIdx.x * EPB;
    for (int base = base0; base < base0 + EPB; base += EG2) {
        __syncthreads();  // WeL staged (1st) / prev chunk msgL+eaL readers done
        // phase 1: taps + dst broadcast list
        if (t < EG2) dstL[t] = s_dst[base + t];
        for (int idx = t; idx < EG2 * NT; idx += 256) {
            int j = idx / NT, i = idx - j * NT;
            float dv = s_d[base + j];
            float v = 0.f;
            if (dv <= 6.34f) {
                int k0 = max(0, min(EDGE_DIM - NT, (int)ceilf(dv * inv_s - 4.5f)));
                float df = dv - (float)(k0 + i) * sp_;
                v = __expf(coeff * df * df);
            }
            eaL[idx] = v;
        }
        // per-lane meta + gather (4 consecutive edges)
        int e0 = base + w * 8 + h * 4;
        float4 a1[4], a2[4];
        int ds_[4], k0_[4];
#pragma unroll
        for (int mm = 0; mm < 4; mm++) {
            int sc = s_src[e0 + mm];
            int dd = s_dst[e0 + mm];
            float dv = s_d[e0 + mm];
            ds_[mm] = dd;
            k0_[mm] = (dv > 6.34f) ? -1
                      : max(0, min(EDGE_DIM - NT, (int)ceilf(dv * inv_s - 4.5f)));
            const float4* p1 = (const float4*)&P1[(size_t)dd * 256];
            const float4* p2 = (const float4*)&P2[(size_t)sc * 256];
            float4 p1a = p1[q], p1b = p1[32 + q];
            float4 p2a = p2[q], p2b = p2[32 + q];
            a1[mm] = make_float4(p1a.x + p2a.x, p1a.y + p2a.y, p1a.z + p2a.z, p1a.w + p2a.w);
            a2[mm] = make_float4(p1b.x + p2b.x, p1b.y + p2b.y, p1b.z + p2b.z, p1b.w + p2b.w);
        }
        __syncthreads();  // eaL ready
        // sparse taps
#pragma unroll
        for (int mm = 0; mm < 4; mm++) {
            int j = w * 8 + h * 4 + mm;
            int k0 = k0_[mm];
            if (k0 >= 0) {
#pragma unroll
                for (int i = 0; i < NT; i++) {
                    float e = eaL[j * NT + i];
                    const uint2* row = (const uint2*)&WeL[(k0 + i) * 256];
                    uint2 u1 = row[q];
                    uint2 u2 = row[32 + q];
                    a1[mm].x = fmaf(__uint_as_float(u1.x << 16), e, a1[mm].x);
                    a1[mm].y = fmaf(__uint_as_float(u1.x & 0xffff0000u), e, a1[mm].y);
                    a1[mm].z = fmaf(__uint_as_float(u1.y << 16), e, a1[mm].z);
                    a1[mm].w = fmaf(__uint_as_float(u1.y & 0xffff0000u), e, a1[mm].w);
                    a2[mm].x = fmaf(__uint_as_float(u2.x << 16), e, a2[mm].x);
                    a2[mm].y = fmaf(__uint_as_float(u2.x & 0xffff0000u), e, a2[mm].y);
                    a2[mm].z = fmaf(__uint_as_float(u2.y << 16), e, a2[mm].z);
                    a2[mm].w = fmaf(__uint_as_float(u2.y & 0xffff0000u), e, a2[mm].w);
                }
            }
        }
        // epilogue -> msgL
#pragma unroll
        for (int mm = 0; mm < 4; mm++) {
            int j = w * 8 + h * 4 + mm;
            float4 z1 = a1[mm], z2 = a2[mm], mg;
            mg.x = sigmoid_f(z1.x) * softplus_f(z2.x);
            mg.y = sigmoid_f(z1.y) * softplus_f(z2.y);
            mg.z = sigmoid_f(z1.z) * softplus_f(z2.z);
            mg.w = sigmoid_f(z1.w) * softplus_f(z2.w);
            *(float4*)&msgL[j * 128 + 4 * q] = mg;
        }
        __syncthreads();  // msgL ready
        // segmented reduce: thread = (channel c, edge half); dense atomics
        int c = t & 127, eb = (t >> 7) * 16, ee = eb + 16;
        float run = 0.f;
        int cur = -1;
        for (int e = eb; e < ee; e++) {
            int dd = dstL[e];
            float v = msgL[e * 128 + c];
            if (dd != cur) {
                if (cur >= 0) atomicAdd(&agg[(size_t)cur * NODE_DIM + c], run);
                run = 0.f;
                cur = dd;
            }
            run += v;
        }
        if (cur >= 0) atomicAdd(&agg[(size_t)cur * NODE_DIM + c], run);
    }
}

// ---------------------------------------------------------------- layernorm + residual + softplus
__global__ void ln_kernel(const float* __restrict__ agg, const float* __restrict__ g,
                          const float* __restrict__ b, float* __restrict__ x) {
    __shared__ float sm[4][2];
    int t = threadIdx.x;
    int r = blockIdx.x * 2 + (t >> 7);
    int c = t & 127;
    float a = agg[(size_t)r * 128 + c];
    float s1 = a, s2 = a * a;
#pragma unroll
    for (int off = 32; off > 0; off >>= 1) {
        s1 += __shfl_xor(s1, off);
        s2 += __shfl_xor(s2, off);
    }
    int wv = t >> 6;
    if ((t & 63) == 0) { sm[wv][0] = s1; sm[wv][1] = s2; }
    __syncthreads();
    int w0 = (t >> 7) * 2;
    float S1 = sm[w0][0] + sm[w0 + 1][0];
    float S2 = sm[w0][1] + sm[w0 + 1][1];
    float mu = S1 * (1.0f / 128.0f);
    float var = S2 * (1.0f / 128.0f) - mu * mu;
    float rstd = rsqrtf(fmaxf(var, 0.f) + 1e-5f);
    float xv = x[(size_t)r * 128 + c];
    x[(size_t)r * 128 + c] = softplus_f((a - mu) * rstd * g[c] + b[c] + xv);
}

// ---------------------------------------------------------------- fused mean-pool + MLP head
__global__ void pool_head_kernel(const float* __restrict__ x, const int* __restrict__ gs,
                                 const float* __restrict__ cfc_w, const float* __restrict__ cfc_b,
                                 const float* __restrict__ fc_w, const float* __restrict__ fc_b,
                                 const float* __restrict__ out_w, const float* __restrict__ out_b,
                                 float* __restrict__ out) {
    int g = blockIdx.x, c = threadIdx.x;  // 128 threads
    int n0 = gs[g], n1 = gs[g + 1];
    float s = 0.f;
    for (int n = n0; n < n1; n++) s += x[(size_t)n * 128 + c];
    __shared__ float h[128], h2[128];
    h[c] = s / fmaxf((float)(n1 - n0), 1.0f);
    __syncthreads();
    float acc = cfc_b[c];
    for (int k = 0; k < 128; k++) acc = fmaf(h[k], cfc_w[k * 128 + c], acc);
    h2[c] = softplus_f(acc);
    __syncthreads();
    for (int l = 0; l < 2; l++) {
        const float* W = fc_w + l * 128 * 128;
        acc = fc_b[l * 128 + c];
        for (int k = 0; k < 128; k++) acc = fmaf(h2[k], W[k * 128 + c], acc);
        __syncthreads();
        h2[c] = softplus_f(acc);
        __syncthreads();
    }
    h[c] = h2[c] * out_w[c];
    __syncthreads();
    for (int off = 64; off > 0; off >>= 1) {
        if (c < off) h[c] += h[c + off];
        __syncthreads();
    }
    if (c == 0) out[g] = h[0] + out_b[0];
}

// ---------------------------------------------------------------- launcher
extern "C" void kernel_launch(void* const* d_in, const int* in_sizes, int n_in,
                              void* d_out, int out_size, void* d_ws, size_t ws_size,
                              hipStream_t stream) {
    const int*   z      = (const int*)d_in[0];
    const float* R      = (const float*)d_in[1];
    const int*   ei     = (const int*)d_in[2];
    const int*   batch  = (const int*)d_in[3];
    const float* emb    = (const float*)d_in[4];
    const float* emb_w  = (const float*)d_in[5];
    const float* emb_b  = (const float*)d_in[6];
    const float* conv_w = (const float*)d_in[7];
    const float* conv_b = (const float*)d_in[8];
    const float* ln_g   = (const float*)d_in[9];
    const float* ln_b   = (const float*)d_in[10];
    const float* cfc_w  = (const float*)d_in[11];
    const float* cfc_b  = (const float*)d_in[12];
    const float* fc_w   = (const float*)d_in[13];
    const float* fc_b   = (const float*)d_in[14];
    const float* out_w  = (const float*)d_in[15];
    const float* out_b  = (const float*)d_in[16];
    float* out = (float*)d_out;

    float* ws    = (float*)d_ws;
    float* x     = ws;                     // 6,400,000
    float* agg   = x + 6400000;            // 6,400,000
    float* P1    = agg + 6400000;          // 12,800,000
    float* P2    = P1 + 12800000;          // 12,800,000
    float* s_d   = P2 + 12800000;          // 800,000
    int* s_src   = (int*)(s_d + 800000);   // 800,000
    int* s_dst   = s_src + 800000;         // 800,000
    int* row_ptr = s_dst + 800000;         // 50,004
    int* deg     = row_ptr + 50004;        // 50,000
    int* cnt2    = deg + 50000;            // 50,000
    int* bsum    = cnt2 + 50000;           // 64
    int* gs      = bsum + 64;              // 260
    __hip_bfloat16* Webf = (__hip_bfloat16*)(gs + 260);  // 76,800 bf16

    hipMemsetAsync(deg, 0, (size_t)100000 * 4, stream);
    deg_kernel<<<(N_EDGES + 255) / 256, 256, 0, stream>>>(ei, deg);
    int nsb = (N_NODES + SB - 1) / SB;  // 49
    scan1_kernel<<<nsb, SB, 0, stream>>>(deg, row_ptr, bsum);
    scan2_kernel<<<1, 64, 0, stream>>>(bsum, nsb);
    scan3_kernel<<<nsb, SB, 0, stream>>>(row_ptr, bsum);
    fill_kernel<<<(N_EDGES + 255) / 256, 256, 0, stream>>>(ei, R, row_ptr, cnt2,
                                                           s_src, s_dst, s_d);
    gb_kernel<<<(N_NODES + 256) / 256 + 1, 256, 0, stream>>>(batch, gs);
    wcvt_kernel<<<(3 * EDGE_DIM * 256 + 255) / 256, 256, 0, stream>>>(conv_w, Webf);

    embed_kernel<<<N_NODES / 8, 128, 0, stream>>>(z, emb, emb_w, emb_b, x);
    for (int l = 0; l < 3; l++) {
        const float* Wl = conv_w + (size_t)l * 356 * 256;
        node_pre_kernel<<<N_NODES / NPB2, 256, 0, stream>>>(x, Wl, conv_b + l * 256, P1, P2);
        hipMemsetAsync(agg, 0, (size_t)6400000 * 4, stream);
        edge_fused3<<<N_EDGES / EPB, 256, 0, stream>>>(s_src, s_dst, s_d, P1, P2,
                                                       Webf + (size_t)l * EDGE_DIM * 256, agg);
        ln_kernel<<<N_NODES / 2, 256, 0, stream>>>(agg, ln_g + l * 128, ln_b + l * 128, x);
    }
    pool_head_kernel<<<N_GRAPHS, 128, 0, stream>>>(x, gs, cfc_w, cfc_b, fc_w, fc_b,
                                                   out_w, out_b, out);
}

// Round 8
// 1226.102 us; speedup vs baseline: 2.4822x; 1.1523x over previous
//
#include <hip/hip_runtime.h>
#include <hip/hip_bf16.h>
#include <cmath>

#define N_NODES 50000
#define N_EDGES 800000
#define NODE_DIM 128
#define EDGE_DIM 100
#define EMB_DIM 92
#define N_GRAPHS 256

typedef __attribute__((ext_vector_type(8))) short short8_t;
typedef __attribute__((ext_vector_type(4))) float float4_t;

__device__ __forceinline__ float softplus_f(float v) {
    return v > 20.0f ? v : __logf(1.0f + __expf(v));
}
__device__ __forceinline__ float sigmoid_f(float v) {
    return 1.0f / (1.0f + __expf(-v));
}
__device__ __forceinline__ float bflo(unsigned u) { return __uint_as_float(u << 16); }
__device__ __forceinline__ float bfhi(unsigned u) { return __uint_as_float(u & 0xffff0000u); }

// ---------------------------------------------------------------- CSR build
__global__ void deg_kernel(const int* __restrict__ ei, int* __restrict__ deg) {
    int e = blockIdx.x * blockDim.x + threadIdx.x;
    if (e >= N_EDGES) return;
    atomicAdd(&deg[ei[N_EDGES + e]], 1);
}

#define SB 1024
__global__ void scan1_kernel(const int* __restrict__ deg, int* __restrict__ rp,
                             int* __restrict__ bsum) {
    __shared__ int buf[SB];
    int b = blockIdx.x, t = threadIdx.x, i = b * SB + t;
    int v = (i < N_NODES) ? deg[i] : 0;
    buf[t] = v;
    __syncthreads();
    for (int off = 1; off < SB; off <<= 1) {
        int a = (t >= off) ? buf[t - off] : 0;
        __syncthreads();
        buf[t] += a;
        __syncthreads();
    }
    if (i < N_NODES) rp[i] = buf[t] - v;
    if (t == SB - 1) bsum[b] = buf[t];
}
__global__ void scan2_kernel(int* __restrict__ bsum, int n) {
    if (threadIdx.x == 0) {
        int s = 0;
        for (int i = 0; i < n; i++) { int v = bsum[i]; bsum[i] = s; s += v; }
    }
}
__global__ void scan3_kernel(int* __restrict__ rp, const int* __restrict__ bsum) {
    int i = blockIdx.x * SB + threadIdx.x;
    if (i < N_NODES) rp[i] += bsum[blockIdx.x];
    if (i == 0) rp[N_NODES] = N_EDGES;
}

__global__ void fill_kernel(const int* __restrict__ ei, const float* __restrict__ R,
                            const int* __restrict__ row_ptr, int* __restrict__ cnt2,
                            int* __restrict__ s_src, int* __restrict__ s_dst,
                            float* __restrict__ s_d) {
    int e = blockIdx.x * blockDim.x + threadIdx.x;
    if (e >= N_EDGES) return;
    int s = ei[e];
    int dst = ei[N_EDGES + e];
    float dx = R[3 * s + 0] - R[3 * dst + 0];
    float dy = R[3 * s + 1] - R[3 * dst + 1];
    float dz = R[3 * s + 2] - R[3 * dst + 2];
    float d = sqrtf(dx * dx + dy * dy + dz * dz);
    int pos = row_ptr[dst] + atomicAdd(&cnt2[dst], 1);
    s_src[pos] = s;
    s_dst[pos] = dst;
    s_d[pos] = d;
}

// ---------------------------------------------------------------- graph boundaries
__global__ void gb_kernel(const int* __restrict__ batch, int* __restrict__ gs) {
    int i = blockIdx.x * 256 + threadIdx.x;
    if (i > N_NODES) return;
    int b = (i < N_NODES) ? batch[i] : N_GRAPHS;
    int pb = (i == 0) ? -1 : batch[i - 1];
    for (int g = pb + 1; g <= b; g++) gs[g] = i;
}

// ---------------------------------------------------------------- We -> bf16 (edge part)
__global__ void wcvt_kernel(const float* __restrict__ conv_w, __hip_bfloat16* __restrict__ Webf) {
    int i = blockIdx.x * 256 + threadIdx.x;
    if (i >= 3 * EDGE_DIM * 256) return;
    int l = i / (EDGE_DIM * 256), r = i - l * (EDGE_DIM * 256);
    Webf[i] = (__hip_bfloat16)conv_w[(size_t)l * 356 * 256 + 256 * 256 + r];
}

// ---------------------------------------------------------------- W1|W2 -> MFMA B-fragment layout
// WbB[l][kc][nt][lane][j], k = kc*32+(lane>>4)*8+j, col = (nt%16)*16+(lane&15),
// conv row = (nt<16 ? k : 128+k). N' = 512 (W1 cols 0..255, W2 cols 256..511).
__global__ void wprep_kernel(const float* __restrict__ conv_w, short* __restrict__ WbB) {
    int idx = blockIdx.x * 256 + threadIdx.x;
    if (idx >= 3 * 4 * 32 * 64 * 8) return;
    int j = idx & 7;
    int lane = (idx >> 3) & 63;
    int nt = (idx >> 9) & 31;
    int kc = (idx >> 14) & 3;
    int l = idx >> 16;
    int k = kc * 32 + (lane >> 4) * 8 + j;
    int nl = lane & 15;
    int row, col;
    if (nt < 16) { row = k; col = nt * 16 + nl; }
    else { row = 128 + k; col = (nt - 16) * 16 + nl; }
    __hip_bfloat16 bv = (__hip_bfloat16)conv_w[(size_t)l * 356 * 256 + (size_t)row * 256 + col];
    WbB[idx] = *(short*)&bv;
}

// ---------------------------------------------------------------- embedding (writes x fp32 + xb bf16)
__global__ void embed_kernel(const int* __restrict__ z, const float* __restrict__ emb,
                             const float* __restrict__ emb_w, const float* __restrict__ emb_b,
                             float* __restrict__ x, __hip_bfloat16* __restrict__ xb) {
    __shared__ float er[EMB_DIM * 8];
    __shared__ int zi[8];
    int base = blockIdx.x * 8;
    int t = threadIdx.x;  // 0..127
    if (t < 8) zi[t] = z[base + t];
    __syncthreads();
    for (int idx = t; idx < EMB_DIM * 8; idx += 128) {
        int k = idx >> 3, j = idx & 7;
        er[idx] = emb[zi[j] * EMB_DIM + k];
    }
    __syncthreads();
    float acc[8];
    float bb = emb_b[t];
#pragma unroll
    for (int j = 0; j < 8; j++) acc[j] = bb;
    for (int k = 0; k < EMB_DIM; k++) {
        float w = emb_w[k * NODE_DIM + t];
        float4 ja = *(const float4*)&er[k * 8];
        float4 jb = *(const float4*)&er[k * 8 + 4];
        acc[0] = fmaf(w, ja.x, acc[0]); acc[1] = fmaf(w, ja.y, acc[1]);
        acc[2] = fmaf(w, ja.z, acc[2]); acc[3] = fmaf(w, ja.w, acc[3]);
        acc[4] = fmaf(w, jb.x, acc[4]); acc[5] = fmaf(w, jb.y, acc[5]);
        acc[6] = fmaf(w, jb.z, acc[6]); acc[7] = fmaf(w, jb.w, acc[7]);
    }
#pragma unroll
    for (int j = 0; j < 8; j++) {
        x[(base + j) * NODE_DIM + t] = acc[j];
        xb[(base + j) * NODE_DIM + t] = (__hip_bfloat16)acc[j];
    }
}

// ---------------------------------------------------------------- node GEMM via MFMA
// C[16 x 512] = Xb[16 x 128] @ (W1|W2); P1 = C[:,0:256]+b, P2 = C[:,256:512].
// 4 waves/block; wave w does N-tiles w*8..w*8+7; K-loop 4 chunks of 32.
__global__ __launch_bounds__(256) void node_mfma_kernel(
    const __hip_bfloat16* __restrict__ xb, const short* __restrict__ WbB,
    const float* __restrict__ bl, float* __restrict__ P1, float* __restrict__ P2) {
    int t = threadIdx.x;
    int wv = t >> 6, lane = t & 63;
    int mrow = lane & 15, q = lane >> 4;
    int base = blockIdx.x * 16;
    const short* xr = (const short*)xb + (size_t)(base + mrow) * 128 + q * 8;
    float4_t acc[8];
#pragma unroll
    for (int i = 0; i < 8; i++) acc[i] = (float4_t){0.f, 0.f, 0.f, 0.f};
#pragma unroll
    for (int kc = 0; kc < 4; kc++) {
        short8_t a = *(const short8_t*)(xr + kc * 32);
#pragma unroll
        for (int i = 0; i < 8; i++) {
            int nt = wv * 8 + i;
            short8_t b = *(const short8_t*)&WbB[((size_t)(kc * 32 + nt) * 64 + lane) * 8];
            acc[i] = __builtin_amdgcn_mfma_f32_16x16x32_bf16(a, b, acc[i], 0, 0, 0);
        }
    }
    // D layout: col = lane&15, row = (lane>>4)*4 + reg
#pragma unroll
    for (int i = 0; i < 8; i++) {
        int nt = wv * 8 + i;
        int np = nt * 16 + mrow;
        if (np < 256) {
            float bb = bl[np];
#pragma unroll
            for (int r = 0; r < 4; r++)
                P1[(size_t)(base + q * 4 + r) * 256 + np] = acc[i][r] + bb;
        } else {
#pragma unroll
            for (int r = 0; r < 4; r++)
                P2[(size_t)(base + q * 4 + r) * 256 + (np - 256)] = acc[i][r];
        }
    }
}

// ---------------------------------------------------------------- edge msg v8: pipelined raw barriers
// Round-4 proven structure (LDS WeL, msgL segmented reduce, dense atomics) but:
// in-lane taps (no eaL phase), meta prefetch depth 2, P-gather prefetch depth 1,
// and lgkm-only s_waitcnt + raw s_barrier so gathers stay in flight across barriers.
#define NTAP 10
#define EG 32
#define EPB 800  // 1000 blocks, 25 chunks each
__device__ __forceinline__ void gather_quad(const float* __restrict__ P1,
                                            const float* __restrict__ P2,
                                            int4 dd, int4 sc, int q,
                                            float4* p1a, float4* p2a,
                                            float4* p1b, float4* p2b) {
    int dds[4] = {dd.x, dd.y, dd.z, dd.w};
    int scs[4] = {sc.x, sc.y, sc.z, sc.w};
#pragma unroll
    for (int m = 0; m < 4; m++) {
        const float4* r1 = (const float4*)&P1[(size_t)dds[m] * 256];
        const float4* r2 = (const float4*)&P2[(size_t)scs[m] * 256];
        p1a[m] = r1[q]; p1b[m] = r1[32 + q];
        p2a[m] = r2[q]; p2b[m] = r2[32 + q];
    }
}

__global__ __launch_bounds__(256, 2) void edge_fused6(
    const int* __restrict__ s_src, const int* __restrict__ s_dst,
    const float* __restrict__ s_d,
    const float* __restrict__ P1, const float* __restrict__ P2,
    const __hip_bfloat16* __restrict__ Webf, float* __restrict__ agg) {
    __shared__ __hip_bfloat16 WeL[EDGE_DIM * 256];  // 51200 B
    __shared__ float msgL[EG * 128];                // 16384 B
    __shared__ int dstL[EG];
    int t = threadIdx.x;
    {
        const float4* s4 = (const float4*)Webf;
        float4* d4 = (float4*)WeL;
        for (int i = t; i < 3200; i += 256) d4[i] = s4[i];
    }
    const float sp_ = 6.0f / 99.0f;
    const float inv_s = 99.0f / 6.0f;
    const float coeff = -0.5f * inv_s * inv_s;
    int w = t >> 6, lane = t & 63, h = lane >> 5, q = lane & 31;
    int eoff = w * 8 + h * 4;
    int base0 = blockIdx.x * EPB;
    // meta prefetch depth 2
    int4 sc_c, dd_c, sc_n, dd_n;
    float4 dv_c, dv_n;
    {
        int e0 = base0 + eoff;
        sc_c = *(const int4*)&s_src[e0];
        dd_c = *(const int4*)&s_dst[e0];
        dv_c = *(const float4*)&s_d[e0];
        int e1 = min(e0 + EG, N_EDGES - 4);
        sc_n = *(const int4*)&s_src[e1];
        dd_n = *(const int4*)&s_dst[e1];
        dv_n = *(const float4*)&s_d[e1];
    }
    float4 p1a[4], p2a[4], p1b[4], p2b[4];
    gather_quad(P1, P2, dd_c, sc_c, q, p1a, p2a, p1b, p2b);
    __syncthreads();  // WeL staged (full drain, once per kernel)
    const int nch = EPB / EG;
    for (int ci = 0; ci < nch; ci++) {
        int dds[4] = {dd_c.x, dd_c.y, dd_c.z, dd_c.w};
        float dvs[4] = {dv_c.x, dv_c.y, dv_c.z, dv_c.w};
        // in-lane sparse taps into separate accumulators (P loads still in flight)
        float4 t1[4], t2[4];
#pragma unroll
        for (int m = 0; m < 4; m++) {
            t1[m] = make_float4(0.f, 0.f, 0.f, 0.f);
            t2[m] = make_float4(0.f, 0.f, 0.f, 0.f);
        }
#pragma unroll
        for (int m = 0; m < 4; m++) {
            float dv = dvs[m];
            if (dv <= 6.34f) {
                int k0 = max(0, min(EDGE_DIM - NTAP, (int)ceilf(dv * inv_s - 4.5f)));
#pragma unroll
                for (int i = 0; i < NTAP; i++) {
                    float df = dv - (float)(k0 + i) * sp_;
                    float e = __expf(coeff * df * df);
                    const uint2* row = (const uint2*)&WeL[(k0 + i) * 256];
                    uint2 u1 = row[q], u2 = row[32 + q];
                    t1[m].x = fmaf(bflo(u1.x), e, t1[m].x);
                    t1[m].y = fmaf(bfhi(u1.x), e, t1[m].y);
                    t1[m].z = fmaf(bflo(u1.y), e, t1[m].z);
                    t1[m].w = fmaf(bfhi(u1.y), e, t1[m].w);
                    t2[m].x = fmaf(bflo(u2.x), e, t2[m].x);
                    t2[m].y = fmaf(bfhi(u2.x), e, t2[m].y);
                    t2[m].z = fmaf(bflo(u2.y), e, t2[m].z);
                    t2[m].w = fmaf(bfhi(u2.y), e, t2[m].w);
                }
            }
        }
        // combine (waits on P gathers here) + activation
        float4 mg[4];
#pragma unroll
        for (int m = 0; m < 4; m++) {
            float z1x = p1a[m].x + p2a[m].x + t1[m].x;
            float z1y = p1a[m].y + p2a[m].y + t1[m].y;
            float z1z = p1a[m].z + p2a[m].z + t1[m].z;
            float z1w = p1a[m].w + p2a[m].w + t1[m].w;
            float z2x = p1b[m].x + p2b[m].x + t2[m].x;
            float z2y = p1b[m].y + p2b[m].y + t2[m].y;
            float z2z = p1b[m].z + p2b[m].z + t2[m].z;
            float z2w = p1b[m].w + p2b[m].w + t2[m].w;
            mg[m].x = sigmoid_f(z1x) * softplus_f(z2x);
            mg[m].y = sigmoid_f(z1y) * softplus_f(z2y);
            mg[m].z = sigmoid_f(z1z) * softplus_f(z2z);
            mg[m].w = sigmoid_f(z1w) * softplus_f(z2w);
        }
        // barrier A: prev chunk's msgL readers done. lgkm-only; VMEM stays in flight.
        __builtin_amdgcn_s_waitcnt(0xC07F);
        __builtin_amdgcn_s_barrier();
#pragma unroll
        for (int m = 0; m < 4; m++)
            *(float4*)&msgL[(eoff + m) * 128 + 4 * q] = mg[m];
        if (q == 0) {
            dstL[eoff + 0] = dds[0]; dstL[eoff + 1] = dds[1];
            dstL[eoff + 2] = dds[2]; dstL[eoff + 3] = dds[3];
        }
        // rotate meta; prefetch meta ci+2 and P-gathers ci+1 (stay in flight across barrier B)
        sc_c = sc_n; dd_c = dd_n; dv_c = dv_n;
        {
            int e2 = min(base0 + (ci + 2) * EG + eoff, N_EDGES - 4);
            sc_n = *(const int4*)&s_src[e2];
            dd_n = *(const int4*)&s_dst[e2];
            dv_n = *(const float4*)&s_d[e2];
        }
        if (ci + 1 < nch)
            gather_quad(P1, P2, dd_c, sc_c, q, p1a, p2a, p1b, p2b);
        // barrier B: msgL/dstL visible
        __builtin_amdgcn_s_waitcnt(0xC07F);
        __builtin_amdgcn_s_barrier();
        // segmented reduce, same-dst fast path
        int c = t & 127, eb = (t >> 7) * 16;
        int d0 = dstL[eb], dl = dstL[eb + 15];
        if (d0 == dl) {
            float s = 0.f;
#pragma unroll
            for (int e2 = 0; e2 < 16; e2++) s += msgL[(eb + e2) * 128 + c];
            atomicAdd(&agg[(size_t)d0 * NODE_DIM + c], s);
        } else {
            float run = 0.f;
            int cur = -1;
            for (int e2 = eb; e2 < eb + 16; e2++) {
                int dd = dstL[e2];
                float v = msgL[e2 * 128 + c];
                if (dd != cur) {
                    if (cur >= 0) atomicAdd(&agg[(size_t)cur * NODE_DIM + c], run);
                    run = 0.f;
                    cur = dd;
                }
                run += v;
            }
            if (cur >= 0) atomicAdd(&agg[(size_t)cur * NODE_DIM + c], run);
        }
    }
}

// ---------------------------------------------------------------- layernorm + residual + softplus (+ xb)
__global__ void ln_kernel(const float* __restrict__ agg, const float* __restrict__ g,
                          const float* __restrict__ b, float* __restrict__ x,
                          __hip_bfloat16* __restrict__ xb) {
    __shared__ float sm[4][2];
    int t = threadIdx.x;
    int r = blockIdx.x * 2 + (t >> 7);
    int c = t & 127;
    float a = agg[(size_t)r * 128 + c];
    float s1 = a, s2 = a * a;
#pragma unroll
    for (int off = 32; off > 0; off >>= 1) {
        s1 += __shfl_xor(s1, off);
        s2 += __shfl_xor(s2, off);
    }
    int wv = t >> 6;
    if ((t & 63) == 0) { sm[wv][0] = s1; sm[wv][1] = s2; }
    __syncthreads();
    int w0 = (t >> 7) * 2;
    float S1 = sm[w0][0] + sm[w0 + 1][0];
    float S2 = sm[w0][1] + sm[w0 + 1][1];
    float mu = S1 * (1.0f / 128.0f);
    float var = S2 * (1.0f / 128.0f) - mu * mu;
    float rstd = rsqrtf(fmaxf(var, 0.f) + 1e-5f);
    float xv = x[(size_t)r * 128 + c];
    float res = softplus_f((a - mu) * rstd * g[c] + b[c] + xv);
    x[(size_t)r * 128 + c] = res;
    xb[(size_t)r * 128 + c] = (__hip_bfloat16)res;
}

// ---------------------------------------------------------------- fused mean-pool + MLP head
__global__ void pool_head_kernel(const float* __restrict__ x, const int* __restrict__ gs,
                                 const float* __restrict__ cfc_w, const float* __restrict__ cfc_b,
                                 const float* __restrict__ fc_w, const float* __restrict__ fc_b,
                                 const float* __restrict__ out_w, const float* __restrict__ out_b,
                                 float* __restrict__ out) {
    int g = blockIdx.x, c = threadIdx.x;  // 128 threads
    int n0 = gs[g], n1 = gs[g + 1];
    float s = 0.f;
    for (int n = n0; n < n1; n++) s += x[(size_t)n * 128 + c];
    __shared__ float h[128], h2[128];
    h[c] = s / fmaxf((float)(n1 - n0), 1.0f);
    __syncthreads();
    float acc = cfc_b[c];
    for (int k = 0; k < 128; k++) acc = fmaf(h[k], cfc_w[k * 128 + c], acc);
    h2[c] = softplus_f(acc);
    __syncthreads();
    for (int l = 0; l < 2; l++) {
        const float* W = fc_w + l * 128 * 128;
        acc = fc_b[l * 128 + c];
        for (int k = 0; k < 128; k++) acc = fmaf(h2[k], W[k * 128 + c], acc);
        __syncthreads();
        h2[c] = softplus_f(acc);
        __syncthreads();
    }
    h[c] = h2[c] * out_w[c];
    __syncthreads();
    for (int off = 64; off > 0; off >>= 1) {
        if (c < off) h[c] += h[c + off];
        __syncthreads();
    }
    if (c == 0) out[g] = h[0] + out_b[0];
}

// ---------------------------------------------------------------- launcher
extern "C" void kernel_launch(void* const* d_in, const int* in_sizes, int n_in,
                              void* d_out, int out_size, void* d_ws, size_t ws_size,
                              hipStream_t stream) {
    const int*   z      = (const int*)d_in[0];
    const float* R      = (const float*)d_in[1];
    const int*   ei     = (const int*)d_in[2];
    const int*   batch  = (const int*)d_in[3];
    const float* emb    = (const float*)d_in[4];
    const float* emb_w  = (const float*)d_in[5];
    const float* emb_b  = (const float*)d_in[6];
    const float* conv_w = (const float*)d_in[7];
    const float* conv_b = (const float*)d_in[8];
    const float* ln_g   = (const float*)d_in[9];
    const float* ln_b   = (const float*)d_in[10];
    const float* cfc_w  = (const float*)d_in[11];
    const float* cfc_b  = (const float*)d_in[12];
    const float* fc_w   = (const float*)d_in[13];
    const float* fc_b   = (const float*)d_in[14];
    const float* out_w  = (const float*)d_in[15];
    const float* out_b  = (const float*)d_in[16];
    float* out = (float*)d_out;

    float* ws    = (float*)d_ws;
    float* x     = ws;                     // 6,400,000
    float* agg   = x + 6400000;            // 6,400,000
    float* P1    = agg + 6400000;          // 12,800,000
    float* P2    = P1 + 12800000;          // 12,800,000
    float* s_d   = P2 + 12800000;          // 800,000
    int* s_src   = (int*)(s_d + 800000);   // 800,000
    int* s_dst   = s_src + 800000;         // 800,000
    int* row_ptr = s_dst + 800000;         // 50,004
    int* deg     = row_ptr + 50004;        // 50,000
    int* cnt2    = deg + 50000;            // 50,000
    int* bsum    = cnt2 + 50000;           // 64
    int* gs      = bsum + 64;              // 260
    __hip_bfloat16* Webf = (__hip_bfloat16*)(gs + 260);        // 76,800 bf16
    short* WbB           = (short*)(Webf + 76800);             // 196,608 shorts
    __hip_bfloat16* xb   = (__hip_bfloat16*)(WbB + 196608);    // 6,400,000 bf16

    hipMemsetAsync(deg, 0, (size_t)100000 * 4, stream);
    deg_kernel<<<(N_EDGES + 255) / 256, 256, 0, stream>>>(ei, deg);
    int nsb = (N_NODES + SB - 1) / SB;  // 49
    scan1_kernel<<<nsb, SB, 0, stream>>>(deg, row_ptr, bsum);
    scan2_kernel<<<1, 64, 0, stream>>>(bsum, nsb);
    scan3_kernel<<<nsb, SB, 0, stream>>>(row_ptr, bsum);
    fill_kernel<<<(N_EDGES + 255) / 256, 256, 0, stream>>>(ei, R, row_ptr, cnt2,
                                                           s_src, s_dst, s_d);
    gb_kernel<<<(N_NODES + 256) / 256 + 1, 256, 0, stream>>>(batch, gs);
    wcvt_kernel<<<(3 * EDGE_DIM * 256 + 255) / 256, 256, 0, stream>>>(conv_w, Webf);
    wprep_kernel<<<(3 * 4 * 32 * 64 * 8 + 255) / 256, 256, 0, stream>>>(conv_w, WbB);

    embed_kernel<<<N_NODES / 8, 128, 0, stream>>>(z, emb, emb_w, emb_b, x, xb);
    for (int l = 0; l < 3; l++) {
        node_mfma_kernel<<<N_NODES / 16, 256, 0, stream>>>(xb, WbB + (size_t)l * 65536,
                                                           conv_b + l * 256, P1, P2);
        hipMemsetAsync(agg, 0, (size_t)6400000 * 4, stream);
        edge_fused6<<<N_EDGES / EPB, 256, 0, stream>>>(s_src, s_dst, s_d, P1, P2,
                                                       Webf + (size_t)l * EDGE_DIM * 256, agg);
        ln_kernel<<<N_NODES / 2, 256, 0, stream>>>(agg, ln_g + l * 128, ln_b + l * 128, x, xb);
    }
    pool_head_kernel<<<N_GRAPHS, 128, 0, stream>>>(x, gs, cfc_w, cfc_b, fc_w, fc_b,
                                                   out_w, out_b, out);
}